// Round 1
// baseline (1568.249 us; speedup 1.0000x reference)
//
#include <hip/hip_runtime.h>
#include <cstddef>

#define D 128
#define EPSV 1e-9f

__device__ __forceinline__ float bcastf(float v, int l) {
    return __int_as_float(__builtin_amdgcn_readlane(__float_as_int(v), l));
}

__device__ __forceinline__ float wred64(float v) {
    #pragma unroll
    for (int off = 32; off > 0; off >>= 1) v += __shfl_xor(v, off, 64);
    return v;
}

// ---------------------------------------------------------------------------
// Kernel 1: push-style SpMM with HW f32 atomics.
// One wave per edge; lane l handles features [2l, 2l+1] (float2) -> fully
// coalesced 512B gather of x[col] and 512B of global_atomic_add_f32 into
// feat[row]. feat == d_out (in-place accumulation; zeroed by memset first).
// ---------------------------------------------------------------------------
__global__ __launch_bounds__(256) void spmm_atomic_kernel(
    const float* __restrict__ x, const int* __restrict__ erow,
    const int* __restrict__ ecol, const float* __restrict__ eval_,
    float* __restrict__ feat, int nEdges)
{
    const int lane = threadIdx.x & 63;
    int w = (int)((blockIdx.x * blockDim.x + threadIdx.x) >> 6);
    const int nW = (int)((gridDim.x * blockDim.x) >> 6);
    for (int e = w; e < nEdges; e += nW) {
        const int r = erow[e];
        const int c = ecol[e];
        const float v = eval_[e];
        const float2 xv = ((const float2*)(x + (size_t)c * D))[lane];
        float* fr = feat + (size_t)r * D + 2 * lane;
        unsafeAtomicAdd(fr,     v * xv.x);
        unsafeAtomicAdd(fr + 1, v * xv.y);
    }
}

// ---------------------------------------------------------------------------
// Kernel 2: fused  out = layernorm(elu(feat @ W^T + b)) * scale + offset
// W^T staged in LDS as Wt[k][o], padded stride 130 (write: bank step 2,
// read: 2-way alias -- both free). One wave owns 2 node rows / iter; the
// feat row lives across the wave's registers, broadcast via v_readlane
// (constant index after full unroll). Each lane computes outputs [2l,2l+1].
// Row reduction for mean/var stays inside the wave (shfl_xor). In-place.
// ---------------------------------------------------------------------------
__global__ __launch_bounds__(256) void gemm_elu_norm_kernel(
    float* __restrict__ io,
    const float* __restrict__ W, const float* __restrict__ bias,
    const float* __restrict__ scale, const float* __restrict__ offset,
    int nNodes)
{
    __shared__ float Wt[D][D + 2];
    for (int i = threadIdx.x; i < D * D; i += 256) {
        const int o = i >> 7, k = i & 127;   // W[i] coalesced; Wt write 2-way
        Wt[k][o] = W[i];
    }
    __syncthreads();

    const int lane = threadIdx.x & 63;
    const int o0 = lane * 2;
    const float b0 = bias[o0],   b1 = bias[o0 + 1];
    const float sc0 = scale[o0], sc1 = scale[o0 + 1];
    const float of0 = offset[o0], of1 = offset[o0 + 1];

    const int gw = (int)(blockIdx.x * 4 + (threadIdx.x >> 6));
    const int nW = (int)(gridDim.x * 4);

    for (int n0 = gw * 2; n0 < nNodes; n0 += nW * 2) {
        const int n1 = n0 + 1;
        const bool has1 = (n1 < nNodes);
        const float2 fa = ((const float2*)(io + (size_t)n0 * D))[lane];
        const float2 fb = has1 ? ((const float2*)(io + (size_t)n1 * D))[lane]
                               : make_float2(0.f, 0.f);
        float a00 = b0, a01 = b1, a10 = b0, a11 = b1;
        #pragma unroll
        for (int kk = 0; kk < 64; ++kk) {
            const float2 w0 = *(const float2*)&Wt[2 * kk][o0];
            const float2 w1 = *(const float2*)&Wt[2 * kk + 1][o0];
            const float fa0 = bcastf(fa.x, kk), fa1 = bcastf(fa.y, kk);
            const float fb0 = bcastf(fb.x, kk), fb1 = bcastf(fb.y, kk);
            a00 = fmaf(fa0, w0.x, a00); a00 = fmaf(fa1, w1.x, a00);
            a01 = fmaf(fa0, w0.y, a01); a01 = fmaf(fa1, w1.y, a01);
            a10 = fmaf(fb0, w0.x, a10); a10 = fmaf(fb1, w1.x, a10);
            a11 = fmaf(fb0, w0.y, a11); a11 = fmaf(fb1, w1.y, a11);
        }
        {
            const float e0 = a00 > 0.f ? a00 : expm1f(a00);
            const float e1 = a01 > 0.f ? a01 : expm1f(a01);
            const float s  = wred64(e0 + e1);
            const float sq = wred64(e0 * e0 + e1 * e1);
            const float mean = s * (1.0f / D);
            const float var  = sq * (1.0f / D) - mean * mean;
            const float rs   = rsqrtf(var + EPSV);
            ((float2*)(io + (size_t)n0 * D))[lane] =
                make_float2((e0 - mean) * sc0 * rs + of0,
                            (e1 - mean) * sc1 * rs + of1);
        }
        if (has1) {
            const float e0 = a10 > 0.f ? a10 : expm1f(a10);
            const float e1 = a11 > 0.f ? a11 : expm1f(a11);
            const float s  = wred64(e0 + e1);
            const float sq = wred64(e0 * e0 + e1 * e1);
            const float mean = s * (1.0f / D);
            const float var  = sq * (1.0f / D) - mean * mean;
            const float rs   = rsqrtf(var + EPSV);
            ((float2*)(io + (size_t)n1 * D))[lane] =
                make_float2((e0 - mean) * sc0 * rs + of0,
                            (e1 - mean) * sc1 * rs + of1);
        }
    }
}

extern "C" void kernel_launch(void* const* d_in, const int* in_sizes, int n_in,
                              void* d_out, int out_size, void* d_ws, size_t ws_size,
                              hipStream_t stream) {
    const float* x      = (const float*)d_in[0];
    const int*   erow   = (const int*)d_in[1];
    const int*   ecol   = (const int*)d_in[2];
    const float* eval_  = (const float*)d_in[3];
    const float* W      = (const float*)d_in[4];
    const float* bias   = (const float*)d_in[5];
    const float* scale  = (const float*)d_in[6];
    const float* offset = (const float*)d_in[7];
    float* out = (float*)d_out;

    const int nE = in_sizes[1];
    const int nN = in_sizes[0] / D;

    hipMemsetAsync(out, 0, (size_t)nN * D * sizeof(float), stream);
    spmm_atomic_kernel<<<2048, 256, 0, stream>>>(x, erow, ecol, eval_, out, nE);
    gemm_elu_norm_kernel<<<512, 256, 0, stream>>>(out, W, bias, scale, offset, nN);
}

// Round 2
// 570.842 us; speedup vs baseline: 2.7473x; 2.7473x over previous
//
#include <hip/hip_runtime.h>
#include <cstddef>

#define D 128
#define EPSV 1e-9f

__device__ __forceinline__ float bcastf(float v, int l) {
    return __int_as_float(__builtin_amdgcn_readlane(__float_as_int(v), l));
}

__device__ __forceinline__ float wred64(float v) {
    #pragma unroll
    for (int off = 32; off > 0; off >>= 1) v += __shfl_xor(v, off, 64);
    return v;
}

// ===========================================================================
// CSR build: histogram -> 3-stage exclusive scan -> scatter (col,val) by row
// ===========================================================================
__global__ __launch_bounds__(256) void hist_kernel(
    const int* __restrict__ erow, int* __restrict__ counts, int nE)
{
    int i = blockIdx.x * 256 + threadIdx.x;
    if (i < nE) atomicAdd(&counts[erow[i]], 1);
}

// block-level exclusive scan of 1024 ints; writes block total to sums[]
__global__ __launch_bounds__(1024) void scan1_kernel(
    const int* __restrict__ in, int* __restrict__ out,
    int* __restrict__ sums, int n)
{
    __shared__ int tmp[1024];
    const int t = threadIdx.x;
    const int gid = blockIdx.x * 1024 + t;
    const int v = (gid < n) ? in[gid] : 0;
    tmp[t] = v;
    __syncthreads();
    #pragma unroll
    for (int d = 1; d < 1024; d <<= 1) {
        int u = (t >= d) ? tmp[t - d] : 0;
        __syncthreads();
        tmp[t] += u;
        __syncthreads();
    }
    if (gid < n) out[gid] = tmp[t] - v;           // exclusive
    if (t == 1023) sums[blockIdx.x] = tmp[t];     // block total
}

// single-block exclusive scan over <=1024 block sums (in place)
__global__ __launch_bounds__(1024) void scan2_kernel(int* __restrict__ sums, int nb)
{
    __shared__ int tmp[1024];
    const int t = threadIdx.x;
    const int v = (t < nb) ? sums[t] : 0;
    tmp[t] = v;
    __syncthreads();
    #pragma unroll
    for (int d = 1; d < 1024; d <<= 1) {
        int u = (t >= d) ? tmp[t - d] : 0;
        __syncthreads();
        tmp[t] += u;
        __syncthreads();
    }
    if (t < nb) sums[t] = tmp[t] - v;
}

__global__ __launch_bounds__(1024) void scan3_kernel(
    int* __restrict__ out, const int* __restrict__ sums, int n)
{
    int gid = blockIdx.x * 1024 + threadIdx.x;
    if (gid < n) out[gid] += sums[blockIdx.x];
}

__global__ __launch_bounds__(256) void scatter_kernel(
    const int* __restrict__ erow, const int* __restrict__ ecol,
    const float* __restrict__ eval_, const int* __restrict__ rowptr,
    int* __restrict__ fill, int2* __restrict__ esort, int nE)
{
    int i = blockIdx.x * 256 + threadIdx.x;
    if (i < nE) {
        const int r = erow[i];
        const int pos = rowptr[r] + atomicAdd(&fill[r], 1);
        esort[pos] = make_int2(ecol[i], __float_as_int(eval_[i]));
    }
}

// ===========================================================================
// Pull SpMM: one wave per node. Scalar walk of the node's CSR list, coalesced
// 512B gathers of x[col] (L3-resident), register accumulate, one feat write.
// ===========================================================================
__global__ __launch_bounds__(256) void spmm_pull_kernel(
    const float* __restrict__ x, const int* __restrict__ rowptr,
    const int2* __restrict__ es, float* __restrict__ feat, int nN)
{
    const int lane = threadIdx.x & 63;
    const int node = __builtin_amdgcn_readfirstlane(
        (int)((blockIdx.x * 256 + threadIdx.x) >> 6));
    if (node >= nN) return;
    const int s = rowptr[node];
    const int e = rowptr[node + 1];
    float2 acc = make_float2(0.f, 0.f);
    int j = s;
    for (; j + 1 < e; j += 2) {
        const int2 e0 = es[j];
        const int2 e1 = es[j + 1];
        const float v0 = __int_as_float(e0.y);
        const float v1 = __int_as_float(e1.y);
        const float2 x0 = ((const float2*)(x + (size_t)e0.x * D))[lane];
        const float2 x1 = ((const float2*)(x + (size_t)e1.x * D))[lane];
        acc.x = fmaf(v0, x0.x, acc.x);
        acc.y = fmaf(v0, x0.y, acc.y);
        acc.x = fmaf(v1, x1.x, acc.x);
        acc.y = fmaf(v1, x1.y, acc.y);
    }
    if (j < e) {
        const int2 e0 = es[j];
        const float v0 = __int_as_float(e0.y);
        const float2 x0 = ((const float2*)(x + (size_t)e0.x * D))[lane];
        acc.x = fmaf(v0, x0.x, acc.x);
        acc.y = fmaf(v0, x0.y, acc.y);
    }
    ((float2*)(feat + (size_t)node * D))[lane] = acc;
}

// ===========================================================================
// Fallback (ws too small): push-style SpMM with HW f32 atomics (round-1 path)
// ===========================================================================
__global__ __launch_bounds__(256) void spmm_atomic_kernel(
    const float* __restrict__ x, const int* __restrict__ erow,
    const int* __restrict__ ecol, const float* __restrict__ eval_,
    float* __restrict__ feat, int nEdges)
{
    const int lane = threadIdx.x & 63;
    int w = (int)((blockIdx.x * blockDim.x + threadIdx.x) >> 6);
    const int nW = (int)((gridDim.x * blockDim.x) >> 6);
    for (int e = w; e < nEdges; e += nW) {
        const int r = erow[e];
        const int c = ecol[e];
        const float v = eval_[e];
        const float2 xv = ((const float2*)(x + (size_t)c * D))[lane];
        float* fr = feat + (size_t)r * D + 2 * lane;
        unsafeAtomicAdd(fr,     v * xv.x);
        unsafeAtomicAdd(fr + 1, v * xv.y);
    }
}

// ===========================================================================
// Kernel 2: fused  out = layernorm(elu(feat @ W^T + b)) * scale + offset
// (unchanged from round 1; in-place on d_out)
// ===========================================================================
__global__ __launch_bounds__(256) void gemm_elu_norm_kernel(
    float* __restrict__ io,
    const float* __restrict__ W, const float* __restrict__ bias,
    const float* __restrict__ scale, const float* __restrict__ offset,
    int nNodes)
{
    __shared__ float Wt[D][D + 2];
    for (int i = threadIdx.x; i < D * D; i += 256) {
        const int o = i >> 7, k = i & 127;
        Wt[k][o] = W[i];
    }
    __syncthreads();

    const int lane = threadIdx.x & 63;
    const int o0 = lane * 2;
    const float b0 = bias[o0],   b1 = bias[o0 + 1];
    const float sc0 = scale[o0], sc1 = scale[o0 + 1];
    const float of0 = offset[o0], of1 = offset[o0 + 1];

    const int gw = (int)(blockIdx.x * 4 + (threadIdx.x >> 6));
    const int nW = (int)(gridDim.x * 4);

    for (int n0 = gw * 2; n0 < nNodes; n0 += nW * 2) {
        const int n1 = n0 + 1;
        const bool has1 = (n1 < nNodes);
        const float2 fa = ((const float2*)(io + (size_t)n0 * D))[lane];
        const float2 fb = has1 ? ((const float2*)(io + (size_t)n1 * D))[lane]
                               : make_float2(0.f, 0.f);
        float a00 = b0, a01 = b1, a10 = b0, a11 = b1;
        #pragma unroll
        for (int kk = 0; kk < 64; ++kk) {
            const float2 w0 = *(const float2*)&Wt[2 * kk][o0];
            const float2 w1 = *(const float2*)&Wt[2 * kk + 1][o0];
            const float fa0 = bcastf(fa.x, kk), fa1 = bcastf(fa.y, kk);
            const float fb0 = bcastf(fb.x, kk), fb1 = bcastf(fb.y, kk);
            a00 = fmaf(fa0, w0.x, a00); a00 = fmaf(fa1, w1.x, a00);
            a01 = fmaf(fa0, w0.y, a01); a01 = fmaf(fa1, w1.y, a01);
            a10 = fmaf(fb0, w0.x, a10); a10 = fmaf(fb1, w1.x, a10);
            a11 = fmaf(fb0, w0.y, a11); a11 = fmaf(fb1, w1.y, a11);
        }
        {
            const float e0 = a00 > 0.f ? a00 : expm1f(a00);
            const float e1 = a01 > 0.f ? a01 : expm1f(a01);
            const float s  = wred64(e0 + e1);
            const float sq = wred64(e0 * e0 + e1 * e1);
            const float mean = s * (1.0f / D);
            const float var  = sq * (1.0f / D) - mean * mean;
            const float rs   = rsqrtf(var + EPSV);
            ((float2*)(io + (size_t)n0 * D))[lane] =
                make_float2((e0 - mean) * sc0 * rs + of0,
                            (e1 - mean) * sc1 * rs + of1);
        }
        if (has1) {
            const float e0 = a10 > 0.f ? a10 : expm1f(a10);
            const float e1 = a11 > 0.f ? a11 : expm1f(a11);
            const float s  = wred64(e0 + e1);
            const float sq = wred64(e0 * e0 + e1 * e1);
            const float mean = s * (1.0f / D);
            const float var  = sq * (1.0f / D) - mean * mean;
            const float rs   = rsqrtf(var + EPSV);
            ((float2*)(io + (size_t)n1 * D))[lane] =
                make_float2((e0 - mean) * sc0 * rs + of0,
                            (e1 - mean) * sc1 * rs + of1);
        }
    }
}

extern "C" void kernel_launch(void* const* d_in, const int* in_sizes, int n_in,
                              void* d_out, int out_size, void* d_ws, size_t ws_size,
                              hipStream_t stream) {
    const float* x      = (const float*)d_in[0];
    const int*   erow   = (const int*)d_in[1];
    const int*   ecol   = (const int*)d_in[2];
    const float* eval_  = (const float*)d_in[3];
    const float* W      = (const float*)d_in[4];
    const float* bias   = (const float*)d_in[5];
    const float* scale  = (const float*)d_in[6];
    const float* offset = (const float*)d_in[7];
    float* out = (float*)d_out;

    const int nE = in_sizes[1];
    const int nN = in_sizes[0] / D;

    // workspace layout
    size_t off = 0;
    auto take = [&](size_t bytes) {
        size_t o = off;
        off = (off + bytes + 255) & ~(size_t)255;
        return o;
    };
    const size_t o_counts = take((size_t)(nN + 1) * 4);
    const size_t o_rowptr = take((size_t)(nN + 1) * 4);
    const size_t o_sums   = take(1024 * 4);
    const size_t o_fill   = take((size_t)nN * 4);
    const size_t o_esort  = take((size_t)nE * 8);
    const bool use_csr = (ws_size >= off);

    if (use_csr) {
        char* ws = (char*)d_ws;
        int*  counts = (int*)(ws + o_counts);
        int*  rowptr = (int*)(ws + o_rowptr);
        int*  sums   = (int*)(ws + o_sums);
        int*  fill   = (int*)(ws + o_fill);
        int2* esort  = (int2*)(ws + o_esort);

        hipMemsetAsync(counts, 0, (size_t)(nN + 1) * 4, stream);
        hipMemsetAsync(fill,   0, (size_t)nN * 4, stream);

        hist_kernel<<<(nE + 255) / 256, 256, 0, stream>>>(erow, counts, nE);

        const int nScan = nN + 1;
        const int nb = (nScan + 1023) / 1024;   // 98 for N=100000
        scan1_kernel<<<nb, 1024, 0, stream>>>(counts, rowptr, sums, nScan);
        scan2_kernel<<<1, 1024, 0, stream>>>(sums, nb);
        scan3_kernel<<<nb, 1024, 0, stream>>>(rowptr, sums, nScan);

        scatter_kernel<<<(nE + 255) / 256, 256, 0, stream>>>(
            erow, ecol, eval_, rowptr, fill, esort, nE);

        spmm_pull_kernel<<<(nN + 3) / 4, 256, 0, stream>>>(
            x, rowptr, esort, out, nN);
    } else {
        hipMemsetAsync(out, 0, (size_t)nN * D * sizeof(float), stream);
        spmm_atomic_kernel<<<2048, 256, 0, stream>>>(x, erow, ecol, eval_, out, nE);
    }

    gemm_elu_norm_kernel<<<1568, 256, 0, stream>>>(out, W, bias, scale, offset, nN);
}